// Round 2
// baseline (334.997 us; speedup 1.0000x reference)
//
#include <hip/hip_runtime.h>
#include <math.h>

// Single fused kernel: ONE ray per 64-lane wave.
//
// Phase 1 — cooperative segment search (replaces the old seg_starts kernel +
// workspace round-trip + kernel-launch serialization): ray_id is sorted, so
// seg bounds are lower_bound(ray) and lower_bound(ray+1). Half 0 (lanes 0-31)
// searches target=ray, half 1 searches target=ray+1, each via a 32-ary
// ballot-partitioned search: 5 dependent gather rounds (log32(16M)) instead
// of 24 (binary). Latency is overlapped across the 65536 resident waves.
//
// Phase 2 — composite, 64-sample chunks. Stats of this input (shift=-1,
// interval=0.5, d~N(0,1)): E[-log t] ~= 0.20/sample -> T<1e-3 cutoff (sum
// 6.9) reached after ~34 samples, so one 64-wide chunk terminates ~99.6% of
// rays. t_i = (1+exp(d+shift))^(-interval) == reference (1-alpha) exactly;
// for interval==0.5 (uniform branch) this is rsqrtf(1+exp(d+shift)) -- 1
// transcendental instead of 3. weights_i = T_i - T_{i+1}. Early exit at
// T < 1e-3 bounds output error by ~2e-3 (<< 1.78e-2 threshold).
__launch_bounds__(256, 8)
__global__ void composite_fused(const float* __restrict__ density,
                                const float* __restrict__ rgb,
                                const float* __restrict__ bg,
                                const float* __restrict__ shift_p,
                                const float* __restrict__ interval_p,
                                const int* __restrict__ ray_id,
                                float* __restrict__ out, int N, int M) {
    const int wave = threadIdx.x >> 6;
    const int lane = threadIdx.x & 63;
    const int sl   = lane & 31;          // sub-lane within half
    const int half = lane >> 5;
    const int ray  = blockIdx.x * (blockDim.x >> 6) + wave;

    const float shift = *shift_p;
    const float I  = *interval_p;
    const float nI = -I;

    // ---- Phase 1: 32-ary cooperative lower_bound per half ----
    // Invariant: answer (first i with ray_id[i] >= target) lies in [lo, hi].
    int lo = 0, hi = M;
    const int target = ray + half;
    if (ray >= N) { lo = 0; hi = 0; }
    while (hi - lo > 32) {
        int span = hi - lo;
        int step = (span + 31) >> 5;                   // ceil(span/32)
        int idx  = lo + sl * step;
        bool pred = (idx < hi) && (ray_id[idx] < target);
        unsigned hb = (unsigned)(__ballot(pred) >> (half * 32));
        int c = __popc(hb);                            // monotone: lanes 0..c-1 true
        if (c == 0) { hi = lo; break; }                // ray_id[lo] >= target
        int nhi = lo + c * step; if (nhi > hi) nhi = hi;
        lo = lo + (c - 1) * step;
        hi = nhi;
    }
    if (hi > lo) {                                     // final round: span <= 32
        int idx = lo + sl;
        bool pred = (idx < hi) && (ray_id[idx] < target);
        unsigned hb = (unsigned)(__ballot(pred) >> (half * 32));
        lo += __popc(hb);
    }
    const int s = __shfl(lo, 0, 64);                   // half 0's result
    const int e = __shfl(lo, 32, 64);                  // half 1's result

    // ---- Phase 2: composite ----
    float T = 1.0f;                 // running transmittance (wave-uniform)
    float ar = 0.f, ag = 0.f, ab = 0.f;
    int  base   = s;
    bool active = (base < e);       // wave-uniform loop
    const bool half_pow = (I == 0.5f);

    while (active) {
        int i = base + lane;
        bool valid = (i < e);
        int ic = (i < M - 1) ? i : (M - 1);     // in-bounds, coalesced
        float d  = density[ic];
        float cr = rgb[3 * ic + 0];
        float cg = rgb[3 * ic + 1];
        float cb = rgb[3 * ic + 2];
        float ex = __expf(d + shift);
        float t;
        if (half_pow) t = rsqrtf(1.0f + ex);                 // (1+e)^(-1/2)
        else          t = exp2f(nI * __log2f(1.0f + ex));    // general
        t = valid ? t : 1.0f;

        // inclusive product scan across the full 64-lane wave
        float p = t;
        #pragma unroll
        for (int off = 1; off < 64; off <<= 1) {
            float o = __shfl_up(p, off, 64);
            p *= (lane >= off) ? o : 1.0f;
        }
        float excl = __shfl_up(p, 1, 64);
        if (lane == 0) excl = 1.0f;
        float wgt = T * (excl - p);   // = T_i - T_{i+1}; 0 on invalid lanes
        ar += wgt * cr;
        ag += wgt * cg;
        ab += wgt * cb;

        float chunk = __shfl(p, 63, 64);   // wave-uniform chunk product
        T *= chunk;
        base += 64;
        active = (base < e) && (T >= 1e-3f);
    }

    // rgb reduction across the wave
    #pragma unroll
    for (int off = 32; off > 0; off >>= 1) {
        ar += __shfl_xor(ar, off, 64);
        ag += __shfl_xor(ag, off, 64);
        ab += __shfl_xor(ab, off, 64);
    }

    if (lane == 0 && ray < N) {
        out[3 * ray + 0] = ar + T * bg[0];
        out[3 * ray + 1] = ag + T * bg[1];
        out[3 * ray + 2] = ab + T * bg[2];
    }
}

extern "C" void kernel_launch(void* const* d_in, const int* in_sizes, int n_in,
                              void* d_out, int out_size, void* d_ws, size_t ws_size,
                              hipStream_t stream) {
    const float* density  = (const float*)d_in[0];
    const float* rgb      = (const float*)d_in[1];
    const float* bg       = (const float*)d_in[2];
    const float* shift    = (const float*)d_in[3];
    const float* interval = (const float*)d_in[4];
    const int*   ray_id   = (const int*)d_in[5];

    const int M = in_sizes[0];       // samples
    const int N = out_size / 3;      // rays

    // 4 waves/block, 1 ray per wave -> 4 rays per block
    int raysPerBlock = 4;
    int blocks = (N + raysPerBlock - 1) / raysPerBlock;
    composite_fused<<<blocks, 256, 0, stream>>>(density, rgb, bg, shift,
                                                interval, ray_id,
                                                (float*)d_out, N, M);
}

// Round 3
// 328.312 us; speedup vs baseline: 1.0204x; 1.0204x over previous
//
#include <hip/hip_runtime.h>
#include <math.h>

// Kernel A: segment boundaries via binary search (ray_id is sorted).
// seg_start[r] = first index i with ray_id[i] >= r, for r in [0, N].
// Adjacent r share search paths -> top levels of the tree stay in L1/L2;
// measured cheaper than fusing a cooperative search into the hot kernel (R2).
__global__ void seg_starts_kernel(const int* __restrict__ ray_id, int M, int N,
                                  int* __restrict__ seg_start) {
    int r = blockIdx.x * blockDim.x + threadIdx.x;
    if (r > N) return;
    int lo = 0, hi = M;
    while (lo < hi) {
        int mid = (lo + hi) >> 1;
        if (ray_id[mid] < r) lo = mid + 1;
        else hi = mid;
    }
    seg_start[r] = lo;
}

// Kernel B: ONE ray per 64-lane wave, 64-sample chunks.
// Stats of this input (shift=-1, interval=0.5, d~N(0,1)): E[-log t] ~= 0.20
// per sample -> T<1e-3 cutoff (sum 6.9) reached after ~34 samples, so one
// 64-wide chunk terminates ~99.6% of rays in a single iteration.
// t_i = (1+exp(d+shift))^(-interval) == reference (1-alpha) exactly; for
// interval==0.5 this is rsqrtf(1+exp(d+shift)) (1 transcendental vs 3).
// weights_i = T_i - T_{i+1}.
// rgb loads are DEFERRED until after the transmittance scan and predicated
// on T_i >= 1e-3: the dead-tail suffix (~30/64 lanes) never fetches its
// 12 B of rgb (~23 MB saved in total). Error bound: skipped weight per ray
// <= T at the skip point < 1e-3; plus early-exit tail <1e-3 -> total ~3e-3,
// far below the 1.78e-2 threshold.
__launch_bounds__(256, 8)
__global__ void composite_kernel(const float* __restrict__ density,
                                 const float* __restrict__ rgb,
                                 const float* __restrict__ bg,
                                 const float* __restrict__ shift_p,
                                 const float* __restrict__ interval_p,
                                 const int* __restrict__ seg_start,
                                 float* __restrict__ out, int N, int M) {
    const int wave = threadIdx.x >> 6;
    const int lane = threadIdx.x & 63;
    const int ray  = blockIdx.x * (blockDim.x >> 6) + wave;

    const float shift = *shift_p;
    const float I  = *interval_p;
    const float nI = -I;
    const bool half_pow = (I == 0.5f);   // wave-uniform

    int s = 0, e = 0;
    if (ray < N) { s = seg_start[ray]; e = seg_start[ray + 1]; }

    float T = 1.0f;                 // running transmittance (wave-uniform)
    float ar = 0.f, ag = 0.f, ab = 0.f;
    int  base   = s;
    bool active = (base < e);       // wave-uniform loop

    while (active) {
        int i = base + lane;
        bool valid = (i < e);
        int ic = (i < M - 1) ? i : (M - 1);     // in-bounds, coalesced
        float d  = density[ic];
        float ex = __expf(d + shift);
        float t;
        if (half_pow) t = rsqrtf(1.0f + ex);                 // (1+e)^(-1/2)
        else          t = exp2f(nI * __log2f(1.0f + ex));    // general
        t = valid ? t : 1.0f;

        // inclusive product scan across the full 64-lane wave
        float p = t;
        #pragma unroll
        for (int off = 1; off < 64; off <<= 1) {
            float o = __shfl_up(p, off, 64);
            p *= (lane >= off) ? o : 1.0f;
        }
        float excl = __shfl_up(p, 1, 64);
        if (lane == 0) excl = 1.0f;
        float Texcl = T * excl;           // = T_i for this lane
        float wgt   = Texcl - T * p;      // = T_i - T_{i+1}; 0 on invalid

        // deferred, predicated rgb fetch: live prefix only
        if (valid && Texcl >= 1e-3f) {
            ar += wgt * rgb[3 * ic + 0];
            ag += wgt * rgb[3 * ic + 1];
            ab += wgt * rgb[3 * ic + 2];
        }

        float chunk = __shfl(p, 63, 64);  // wave-uniform chunk product
        T *= chunk;
        base += 64;
        active = (base < e) && (T >= 1e-3f);
    }

    // rgb reduction across the wave
    #pragma unroll
    for (int off = 32; off > 0; off >>= 1) {
        ar += __shfl_xor(ar, off, 64);
        ag += __shfl_xor(ag, off, 64);
        ab += __shfl_xor(ab, off, 64);
    }

    if (lane == 0 && ray < N) {
        out[3 * ray + 0] = ar + T * bg[0];
        out[3 * ray + 1] = ag + T * bg[1];
        out[3 * ray + 2] = ab + T * bg[2];
    }
}

extern "C" void kernel_launch(void* const* d_in, const int* in_sizes, int n_in,
                              void* d_out, int out_size, void* d_ws, size_t ws_size,
                              hipStream_t stream) {
    const float* density  = (const float*)d_in[0];
    const float* rgb      = (const float*)d_in[1];
    const float* bg       = (const float*)d_in[2];
    const float* shift    = (const float*)d_in[3];
    const float* interval = (const float*)d_in[4];
    const int*   ray_id   = (const int*)d_in[5];

    const int M = in_sizes[0];       // samples
    const int N = out_size / 3;      // rays

    int* seg_start = (int*)d_ws;     // N+1 ints

    {
        int threads = 256;
        int blocks = (N + 1 + threads - 1) / threads;
        seg_starts_kernel<<<blocks, threads, 0, stream>>>(ray_id, M, N, seg_start);
    }
    {
        // 4 waves/block, 1 ray per wave -> 4 rays per block
        int raysPerBlock = 4;
        int blocks = (N + raysPerBlock - 1) / raysPerBlock;
        composite_kernel<<<blocks, 256, 0, stream>>>(density, rgb, bg, shift,
                                                     interval, seg_start,
                                                     (float*)d_out, N, M);
    }
}

// Round 4
// 325.205 us; speedup vs baseline: 1.0301x; 1.0096x over previous
//
#include <hip/hip_runtime.h>
#include <math.h>

// Kernel A: segment boundaries via binary search (ray_id is sorted).
// seg_start[r] = first index i with ray_id[i] >= r, for r in [0, N].
// Adjacent r share search paths -> top tree levels stay in L1/L2; measured
// cheaper than fusing a cooperative search into the hot kernel (R2: +11us).
__global__ void seg_starts_kernel(const int* __restrict__ ray_id, int M, int N,
                                  int* __restrict__ seg_start) {
    int r = blockIdx.x * blockDim.x + threadIdx.x;
    if (r > N) return;
    int lo = 0, hi = M;
    while (lo < hi) {
        int mid = (lo + hi) >> 1;
        if (ray_id[mid] < r) lo = mid + 1;
        else hi = mid;
    }
    seg_start[r] = lo;
}

// Kernel B: ONE ray per 64-lane wave, 64-sample chunks (best measured: R1).
// Stats of this input (shift=-1, interval=0.5, d~N(0,1)): E[-log t] ~= 0.20
// per sample -> T<1e-3 cutoff (sum 6.9) reached after ~34 samples, so one
// 64-wide chunk terminates ~99.6% of rays in a single iteration.
// t_i = (1+exp(d+shift))^(-interval) == reference (1-alpha) exactly; for
// interval==0.5 (uniform branch) this is rsqrtf(1+exp(d+shift)).
// weights_i = T_i - T_{i+1}. Early exit at T < 1e-3 bounds output error by
// ~2e-3 (<< 1.78e-2 threshold). rgb loads stay EAGER next to the density
// load: R3 showed predicating them behind the scan (to save ~23 MB) costs
// more in exposed latency than the bandwidth it saves.
__launch_bounds__(256, 8)
__global__ void composite_kernel(const float* __restrict__ density,
                                 const float* __restrict__ rgb,
                                 const float* __restrict__ bg,
                                 const float* __restrict__ shift_p,
                                 const float* __restrict__ interval_p,
                                 const int* __restrict__ seg_start,
                                 float* __restrict__ out, int N, int M) {
    const int wave = threadIdx.x >> 6;
    const int lane = threadIdx.x & 63;
    const int ray  = blockIdx.x * (blockDim.x >> 6) + wave;

    const float shift = *shift_p;
    const float I  = *interval_p;
    const float nI = -I;
    const bool half_pow = (I == 0.5f);   // wave-uniform

    int s = 0, e = 0;
    if (ray < N) { s = seg_start[ray]; e = seg_start[ray + 1]; }

    float T = 1.0f;                 // running transmittance (wave-uniform)
    float ar = 0.f, ag = 0.f, ab = 0.f;
    int  base   = s;
    bool active = (base < e);       // wave-uniform loop

    while (active) {
        int i = base + lane;
        bool valid = (i < e);
        int ic = (i < M - 1) ? i : (M - 1);     // in-bounds, coalesced
        float d  = density[ic];
        float cr = rgb[3 * ic + 0];
        float cg = rgb[3 * ic + 1];
        float cb = rgb[3 * ic + 2];
        float ex = __expf(d + shift);
        float t;
        if (half_pow) t = rsqrtf(1.0f + ex);                 // (1+e)^(-1/2)
        else          t = exp2f(nI * __log2f(1.0f + ex));    // general
        t = valid ? t : 1.0f;

        // inclusive product scan across the full 64-lane wave
        float p = t;
        #pragma unroll
        for (int off = 1; off < 64; off <<= 1) {
            float o = __shfl_up(p, off, 64);
            p *= (lane >= off) ? o : 1.0f;
        }
        float excl = __shfl_up(p, 1, 64);
        if (lane == 0) excl = 1.0f;
        float wgt = T * (excl - p);   // = T_i - T_{i+1}; 0 on invalid lanes
        ar += wgt * cr;
        ag += wgt * cg;
        ab += wgt * cb;

        float chunk = __shfl(p, 63, 64);   // wave-uniform chunk product
        T *= chunk;
        base += 64;
        active = (base < e) && (T >= 1e-3f);
    }

    // rgb reduction across the wave
    #pragma unroll
    for (int off = 32; off > 0; off >>= 1) {
        ar += __shfl_xor(ar, off, 64);
        ag += __shfl_xor(ag, off, 64);
        ab += __shfl_xor(ab, off, 64);
    }

    if (lane == 0 && ray < N) {
        out[3 * ray + 0] = ar + T * bg[0];
        out[3 * ray + 1] = ag + T * bg[1];
        out[3 * ray + 2] = ab + T * bg[2];
    }
}

extern "C" void kernel_launch(void* const* d_in, const int* in_sizes, int n_in,
                              void* d_out, int out_size, void* d_ws, size_t ws_size,
                              hipStream_t stream) {
    const float* density  = (const float*)d_in[0];
    const float* rgb      = (const float*)d_in[1];
    const float* bg       = (const float*)d_in[2];
    const float* shift    = (const float*)d_in[3];
    const float* interval = (const float*)d_in[4];
    const int*   ray_id   = (const int*)d_in[5];

    const int M = in_sizes[0];       // samples
    const int N = out_size / 3;      // rays

    int* seg_start = (int*)d_ws;     // N+1 ints

    {
        int threads = 256;
        int blocks = (N + 1 + threads - 1) / threads;
        seg_starts_kernel<<<blocks, threads, 0, stream>>>(ray_id, M, N, seg_start);
    }
    {
        // 4 waves/block, 1 ray per wave -> 4 rays per block
        int raysPerBlock = 4;
        int blocks = (N + raysPerBlock - 1) / raysPerBlock;
        composite_kernel<<<blocks, 256, 0, stream>>>(density, rgb, bg, shift,
                                                     interval, seg_start,
                                                     (float*)d_out, N, M);
    }
}